// Round 3
// baseline (4155.296 us; speedup 1.0000x reference)
//
#include <hip/hip_runtime.h>
#include <hip/hip_bf16.h>

typedef __hip_bfloat16 bf16;

constexpr int NN = 50000;           // nodes
constexpr int NE = 800000;          // edges (without self loops)
constexpr int NT = NE + NN;         // edges incl self loops

// flag-selected load: f32 storage vs bf16 storage
__device__ __forceinline__ float cvt(const void* p, long long i, int f32){
  return f32 ? ((const float*)p)[i] : __bfloat162float(((const bf16*)p)[i]);
}

// monotone float <-> uint key for atomicMax on floats (any sign)
__device__ __forceinline__ unsigned f2key(float f){
  unsigned u = __float_as_uint(f);
  return (u & 0x80000000u) ? ~u : (u | 0x80000000u);
}
__device__ __forceinline__ float key2f(unsigned k){
  unsigned u = (k & 0x80000000u) ? (k & 0x7fffffffu) : ~k;
  return __uint_as_float(u);
}

// Decide storage dtype of float inputs by scanning W1 as bf16 half-words.
// bf16 weights ~N(0,1/sqrt(128)) have exponent <= ~126. f32 storage scanned as
// u16 half-words exposes mantissa bits -> pseudo-exponents >= 0xC0 appear fast.
// flag=1 => f32 storage, 0 => bf16 storage.
__global__ void k_detect(const void* w, int n, int* flag){
  __shared__ int bad;
  if(threadIdx.x == 0) bad = 0;
  __syncthreads();
  const unsigned short* p = (const unsigned short*)w;
  int local = 0;
  for(int i = threadIdx.x; i < n; i += 256){
    int e = (p[i] >> 7) & 0xFF;
    if(e >= 0xC0) local = 1;
  }
  if(local) atomicOr(&bad, 1);
  __syncthreads();
  if(threadIdx.x == 0) *flag = bad;
}

// convert all 12 weight arrays into contiguous f32 scratch
struct SrcPtrs { const void* p[12]; };
__global__ void k_cvtall(SrcPtrs sp, float* Wc, const int* flag){
  const int sz[12]  = {8192,64,4096,64,8192,128,128,128,8192,64,64,32};
  const int off[12] = {0,8192,8256,12352,12416,20608,20736,20864,20992,29184,29248,29312};
  int b = blockIdx.x;
  int f = *flag;
  const void* src = sp.p[b];
  float* dst = Wc + off[b];
  int n = sz[b];
  for(int i = threadIdx.x; i < n; i += 256) dst[i] = cvt(src, i, f);
}

__global__ void k_fill1(float* __restrict__ p, int n){
  int i = blockIdx.x*256 + threadIdx.x;
  if(i < n) p[i] = 1.0f;   // self-loop contribution to degree
}

__global__ void k_deg(const int* __restrict__ ei, float* __restrict__ deg){
  int e = blockIdx.x*256 + threadIdx.x;
  if(e < NE) atomicAdd(&deg[ei[NE + e]], 1.0f);
}

__global__ void k_rsqrt(float* __restrict__ p, int n){
  int i = blockIdx.x*256 + threadIdx.x;
  if(i < n) p[i] = rsqrtf(p[i]);
}

// C = X @ W  with X read via dtype flag (layer 1 only)
template<int KIN, int KOUT>
__global__ void k_gemm_in(const void* __restrict__ X, const float* __restrict__ W,
                          float* __restrict__ C, const int* __restrict__ flag){
  constexpr int R = 256 / KOUT;
  __shared__ float Wl[KIN * KOUT];
  __shared__ float Xl[R][KIN];
  int tid = threadIdx.y * KOUT + threadIdx.x;
  int f = *flag;
  for(int i = tid; i < KIN*KOUT; i += 256) Wl[i] = W[i];
  int row0 = blockIdx.x * R;
  for(int i = tid; i < R*KIN; i += 256){
    int r = i / KIN, k = i - r*KIN;
    int rr = row0 + r;
    Xl[r][k] = (rr < NN) ? cvt(X, (long long)rr*KIN + k, f) : 0.0f;
  }
  __syncthreads();
  int row = row0 + threadIdx.y;
  if(row >= NN) return;
  float acc = 0.0f;
#pragma unroll
  for(int k = 0; k < KIN; k++) acc += Xl[threadIdx.y][k] * Wl[k*KOUT + threadIdx.x];
  C[row*KOUT + threadIdx.x] = acc;
}

// C = X @ W with f32 X (internal layers)
template<int KIN, int KOUT>
__global__ void k_gemm_f(const float* __restrict__ X, const float* __restrict__ W,
                         float* __restrict__ C){
  constexpr int R = 256 / KOUT;
  __shared__ float Wl[KIN * KOUT];
  __shared__ float Xl[R][KIN];
  int tid = threadIdx.y * KOUT + threadIdx.x;
  for(int i = tid; i < KIN*KOUT; i += 256) Wl[i] = W[i];
  int row0 = blockIdx.x * R;
  for(int i = tid; i < R*KIN; i += 256){
    int r = i / KIN, k = i - r*KIN;
    int rr = row0 + r;
    Xl[r][k] = (rr < NN) ? X[(long long)rr*KIN + k] : 0.0f;
  }
  __syncthreads();
  int row = row0 + threadIdx.y;
  if(row >= NN) return;
  float acc = 0.0f;
#pragma unroll
  for(int k = 0; k < KIN; k++) acc += Xl[threadIdx.y][k] * Wl[k*KOUT + threadIdx.x];
  C[row*KOUT + threadIdx.x] = acc;
}

template<int K>
__global__ void k_bias_relu(float* __restrict__ C, const float* __restrict__ b){
  int i = blockIdx.x*256 + threadIdx.x;
  if(i < NN*K){
    float v = C[i] + b[i & (K-1)];
    C[i] = fmaxf(v, 0.0f);
  }
}

// GCN aggregation: B[dst] += A[src] * dinv[src]*dinv[dst], K/4 threads/edge x float4
template<int K>
__global__ void k_gcn_scatter(const int* __restrict__ ei, const float* __restrict__ dinv,
                              const float* __restrict__ A, float* __restrict__ B){
  constexpr int TPE = K/4;
  int idx = blockIdx.x*256 + threadIdx.x;
  int e = idx / TPE, sub = idx & (TPE-1);
  if(e >= NT) return;
  int src, dst;
  if(e < NE){ src = ei[e]; dst = ei[NE + e]; } else { src = dst = e - NE; }
  float norm = dinv[src]*dinv[dst];
  const float4 v = *reinterpret_cast<const float4*>(A + (long long)src*K + sub*4);
  float* o = B + (long long)dst*K + sub*4;
  atomicAdd(o+0, v.x*norm);
  atomicAdd(o+1, v.y*norm);
  atomicAdd(o+2, v.z*norm);
  atomicAdd(o+3, v.w*norm);
}

// per (node, head) attention scores s = <h, a_src>, d = <h, a_dst>
template<int C>
__global__ void k_gat_scores(const float* __restrict__ Hg, const float* __restrict__ asrc,
                             const float* __restrict__ adst, float* __restrict__ sS, float* __restrict__ sD){
  int i = blockIdx.x*256 + threadIdx.x;
  if(i >= NN*2) return;
  int node = i >> 1, h = i & 1;
  const float* hp = Hg + (long long)node*(2*C) + h*C;
  float s = 0.0f, d = 0.0f;
#pragma unroll
  for(int c = 0; c < C; c++){
    float v = hp[c];
    s += v * asrc[h*C + c];
    d += v * adst[h*C + c];
  }
  sS[i] = s; sD[i] = d;
}

__global__ void k_gat_max(const int* __restrict__ ei, const float* __restrict__ sS,
                          const float* __restrict__ sD, unsigned* __restrict__ mK){
  int idx = blockIdx.x*256 + threadIdx.x;
  int e = idx >> 1, h = idx & 1;
  if(e >= NT) return;
  int src, dst;
  if(e < NE){ src = ei[e]; dst = ei[NE + e]; } else { src = dst = e - NE; }
  float v = sS[src*2 + h] + sD[dst*2 + h];
  v = v > 0.0f ? v : 0.2f*v;           // leaky_relu 0.2
  atomicMax(&mK[dst*2 + h], f2key(v));
}

// unnormalized numerator accumulate + denominator
template<int C>
__global__ void k_gat_accum(const int* __restrict__ ei, const float* __restrict__ sS,
                            const float* __restrict__ sD, const unsigned* __restrict__ mK,
                            float* __restrict__ zS, const float* __restrict__ Hg, float* __restrict__ B){
  constexpr int TPE = 2*C/4;
  int idx = blockIdx.x*256 + threadIdx.x;
  int e = idx / TPE, sub = idx & (TPE-1);
  if(e >= NT) return;
  int src, dst;
  if(e < NE){ src = ei[e]; dst = ei[NE + e]; } else { src = dst = e - NE; }
  int h = (sub*4) / C;
  int ih = dst*2 + h;
  float v = sS[src*2 + h] + sD[ih];
  v = v > 0.0f ? v : 0.2f*v;
  float w = __expf(v - key2f(mK[ih]));
  if(sub == h*(C/4)) atomicAdd(&zS[ih], w);
  const float4 val = *reinterpret_cast<const float4*>(Hg + (long long)src*2*C + sub*4);
  float* o = B + (long long)dst*2*C + sub*4;
  atomicAdd(o+0, val.x*w);
  atomicAdd(o+1, val.y*w);
  atomicAdd(o+2, val.z*w);
  atomicAdd(o+3, val.w*w);
}

// GAT1 epilogue: normalize by z, +bias, relu (concat layout [n, h*C+c])
template<int HC, int C>
__global__ void k_gat_finish_relu(float* __restrict__ B, const float* __restrict__ zS,
                                  const float* __restrict__ bias){
  int i = blockIdx.x*256 + threadIdx.x;
  if(i >= NN*HC) return;
  int node = i / HC; int j = i - node*HC; int h = j / C;
  float v = B[i] / (zS[node*2 + h] + 1e-16f) + bias[j];
  B[i] = fmaxf(v, 0.0f);
}

// GAT2 epilogue: normalize, mean heads, +bias, log_softmax over 32.
// Output dtype mirrors input storage: f32 when flag=1, bf16 when flag=0.
__global__ void k_final(const float* __restrict__ B, const float* __restrict__ zS,
                        const float* __restrict__ bias, void* __restrict__ out,
                        const int* __restrict__ flag){
  int n = blockIdx.x*256 + threadIdx.x;
  if(n >= NN) return;
  int f = *flag;
  float z0 = zS[n*2] + 1e-16f, z1 = zS[n*2+1] + 1e-16f;
  float o[32]; float mx = -1e30f;
#pragma unroll
  for(int c = 0; c < 32; c++){
    float v = 0.5f*(B[(long long)n*64 + c]/z0 + B[(long long)n*64 + 32 + c]/z1) + bias[c];
    o[c] = v; mx = fmaxf(mx, v);
  }
  float s = 0.0f;
#pragma unroll
  for(int c = 0; c < 32; c++) s += __expf(o[c] - mx);
  float lse = mx + logf(s);
  if(f){
    float* po = (float*)out;
#pragma unroll
    for(int c = 0; c < 32; c++) po[(long long)n*32 + c] = o[c] - lse;
  } else {
    bf16* po = (bf16*)out;
#pragma unroll
    for(int c = 0; c < 32; c++) po[(long long)n*32 + c] = __float2bfloat16(o[c] - lse);
  }
}

extern "C" void kernel_launch(void* const* d_in, const int* in_sizes, int n_in,
                              void* d_out, int out_size, void* d_ws, size_t ws_size,
                              hipStream_t stream) {
  const void* x   = d_in[0];
  const int*  ei  = (const int*)d_in[1];

  // workspace layout (f32):
  // A[NN*128] | B[NN*128] | dinv[NN] | sS[2NN] | sD[2NN] | mK[2NN] | zS[2NN] | Wc[29344] | flag
  float* A    = (float*)d_ws;
  float* B    = A + (size_t)NN*128;
  float* dinv = B + (size_t)NN*128;
  float* sS   = dinv + NN;
  float* sD   = sS + 2*NN;
  unsigned* mK = (unsigned*)(sD + 2*NN);
  float* zS   = (float*)(mK + 2*NN);
  float* Wc   = zS + 2*NN;
  int*  flag  = (int*)(Wc + 29344);

  const float* W1c  = Wc;
  const float* b1c  = Wc + 8192;
  const float* W2c  = Wc + 8256;
  const float* b2c  = Wc + 12352;
  const float* Wg1c = Wc + 12416;
  const float* as1c = Wc + 20608;
  const float* ad1c = Wc + 20736;
  const float* bg1c = Wc + 20864;
  const float* Wg2c = Wc + 20992;
  const float* as2c = Wc + 29184;
  const float* ad2c = Wc + 29248;
  const float* bg2c = Wc + 29312;

  auto nb = [](long long t){ return dim3((unsigned)((t + 255)/256)); };

  // dtype detect + weight conversion to f32
  k_detect<<<1, 256, 0, stream>>>(d_in[2], 8192, flag);
  SrcPtrs sp;
  for(int i = 0; i < 12; i++) sp.p[i] = d_in[2 + i];
  k_cvtall<<<12, 256, 0, stream>>>(sp, Wc, flag);

  // symmetric-norm degrees (shared by both GCN layers)
  k_fill1<<<nb(NN), 256, 0, stream>>>(dinv, NN);
  k_deg<<<nb(NE), 256, 0, stream>>>(ei, dinv);
  k_rsqrt<<<nb(NN), 256, 0, stream>>>(dinv, NN);

  // ---- GCN1: relu(Ahat (x@W1) + b1) ----
  k_gemm_in<128,64><<<dim3((NN+3)/4), dim3(64,4), 0, stream>>>(x, W1c, A, flag);
  hipMemsetAsync(B, 0, (size_t)NN*64*4, stream);
  k_gcn_scatter<64><<<nb((long long)NT*16), 256, 0, stream>>>(ei, dinv, A, B);
  k_bias_relu<64><<<nb((long long)NN*64), 256, 0, stream>>>(B, b1c);

  // ---- GCN2 ----
  k_gemm_f<64,64><<<dim3((NN+3)/4), dim3(64,4), 0, stream>>>(B, W2c, A);
  hipMemsetAsync(B, 0, (size_t)NN*64*4, stream);
  k_gcn_scatter<64><<<nb((long long)NT*16), 256, 0, stream>>>(ei, dinv, A, B);
  k_bias_relu<64><<<nb((long long)NN*64), 256, 0, stream>>>(B, b2c);

  // ---- GAT1: heads=2, C=64, concat ----
  k_gemm_f<64,128><<<dim3((NN+1)/2), dim3(128,2), 0, stream>>>(B, Wg1c, A);
  k_gat_scores<64><<<nb((long long)NN*2), 256, 0, stream>>>(A, as1c, ad1c, sS, sD);
  hipMemsetAsync(mK, 0, (size_t)NN*2*4, stream);
  hipMemsetAsync(zS, 0, (size_t)NN*2*4, stream);
  hipMemsetAsync(B, 0, (size_t)NN*128*4, stream);
  k_gat_max<<<nb((long long)NT*2), 256, 0, stream>>>(ei, sS, sD, mK);
  k_gat_accum<64><<<nb((long long)NT*32), 256, 0, stream>>>(ei, sS, sD, mK, zS, A, B);
  k_gat_finish_relu<128,64><<<nb((long long)NN*128), 256, 0, stream>>>(B, zS, bg1c);

  // ---- GAT2: heads=2, C=32, mean ----
  k_gemm_f<128,64><<<dim3((NN+3)/4), dim3(64,4), 0, stream>>>(B, Wg2c, A);
  k_gat_scores<32><<<nb((long long)NN*2), 256, 0, stream>>>(A, as2c, ad2c, sS, sD);
  hipMemsetAsync(mK, 0, (size_t)NN*2*4, stream);
  hipMemsetAsync(zS, 0, (size_t)NN*2*4, stream);
  hipMemsetAsync(B, 0, (size_t)NN*64*4, stream);
  k_gat_max<<<nb((long long)NT*2), 256, 0, stream>>>(ei, sS, sD, mK);
  k_gat_accum<32><<<nb((long long)NT*16), 256, 0, stream>>>(ei, sS, sD, mK, zS, A, B);
  k_final<<<nb(NN), 256, 0, stream>>>(B, zS, bg2c, d_out, flag);
}

// Round 4
// 894.041 us; speedup vs baseline: 4.6478x; 4.6478x over previous
//
#include <hip/hip_runtime.h>
#include <hip/hip_bf16.h>

typedef __hip_bfloat16 bf16;

constexpr int NN = 50000;           // nodes
constexpr int NE = 800000;          // edges (without self loops)
constexpr int NT = NE + NN;         // edges incl self loops

// flag-selected load: f32 storage vs bf16 storage
__device__ __forceinline__ float cvt(const void* p, long long i, int f32){
  return f32 ? ((const float*)p)[i] : __bfloat162float(((const bf16*)p)[i]);
}

// Storage-dtype detector (see R2 notes): flag=1 => f32 storage, 0 => bf16.
__global__ void k_detect(const void* w, int n, int* flag){
  __shared__ int bad;
  if(threadIdx.x == 0) bad = 0;
  __syncthreads();
  const unsigned short* p = (const unsigned short*)w;
  int local = 0;
  for(int i = threadIdx.x; i < n; i += 256){
    int e = (p[i] >> 7) & 0xFF;
    if(e >= 0xC0) local = 1;
  }
  if(local) atomicOr(&bad, 1);
  __syncthreads();
  if(threadIdx.x == 0) *flag = bad;
}

struct SrcPtrs { const void* p[12]; };
__global__ void k_cvtall(SrcPtrs sp, float* Wc, const int* flag){
  const int sz[12]  = {8192,64,4096,64,8192,128,128,128,8192,64,64,32};
  const int off[12] = {0,8192,8256,12352,12416,20608,20736,20864,20992,29184,29248,29312};
  int b = blockIdx.x;
  int f = *flag;
  const void* src = sp.p[b];
  float* dst = Wc + off[b];
  int n = sz[b];
  for(int i = threadIdx.x; i < n; i += 256) dst[i] = cvt(src, i, f);
}

// ---------------- CSR build (dst-bucketed, self-loops included) ----------------
__global__ void k_init_counts(int* __restrict__ counts){
  int i = blockIdx.x*256 + threadIdx.x;
  if(i < NN) counts[i] = 1;          // self loop
}
__global__ void k_count_edges(const int* __restrict__ ei, int* __restrict__ counts){
  int e = blockIdx.x*256 + threadIdx.x;
  if(e < NE) atomicAdd(&counts[ei[NE + e]], 1);
}
// one-block exclusive scan over counts -> rowptr & cursor; also dinv=rsqrt(deg)
__global__ void k_scan(const int* __restrict__ counts, int* __restrict__ rowptr,
                       int* __restrict__ cursor, float* __restrict__ dinv){
  __shared__ int buf[2][1024];
  int t = threadIdx.x;
  constexpr int CH = (NN + 1023)/1024;
  int lo = t*CH, hi = (lo+CH < NN) ? lo+CH : NN;
  int s = 0;
  for(int i = lo; i < hi; i++) s += counts[i];
  buf[0][t] = s;
  __syncthreads();
  int cur = 0;
  for(int off = 1; off < 1024; off <<= 1){
    int nxt = cur^1;
    int v = buf[cur][t];
    if(t >= off) v += buf[cur][t-off];
    buf[nxt][t] = v;
    __syncthreads();
    cur = nxt;
  }
  int base = (t == 0) ? 0 : buf[cur][t-1];
  for(int i = lo; i < hi; i++){
    rowptr[i] = base; cursor[i] = base;
    int c = counts[i];
    dinv[i] = rsqrtf((float)c);
    base += c;
  }
}
// fill: self-loops + edges (order within a bucket irrelevant for sums)
__global__ void k_fill(const int* __restrict__ ei, int* __restrict__ cursor,
                       int* __restrict__ srcidx){
  int idx = blockIdx.x*256 + threadIdx.x;
  if(idx < NN){
    int pos = atomicAdd(&cursor[idx], 1);
    srcidx[pos] = idx;
  } else if(idx < NN + NE){
    int e = idx - NN;
    int dst = ei[NE + e];
    int pos = atomicAdd(&cursor[dst], 1);
    srcidx[pos] = ei[e];
  }
}
// after k_fill, cursor[n] == row end for node n.

// ---------------- dense layers ----------------
template<int KIN, int KOUT>
__global__ void k_gemm_in(const void* __restrict__ X, const float* __restrict__ W,
                          float* __restrict__ C, const int* __restrict__ flag){
  constexpr int R = 256 / KOUT;
  __shared__ float Wl[KIN * KOUT];
  __shared__ float Xl[R][KIN];
  int tid = threadIdx.y * KOUT + threadIdx.x;
  int f = *flag;
  for(int i = tid; i < KIN*KOUT; i += 256) Wl[i] = W[i];
  int row0 = blockIdx.x * R;
  for(int i = tid; i < R*KIN; i += 256){
    int r = i / KIN, k = i - r*KIN;
    int rr = row0 + r;
    Xl[r][k] = (rr < NN) ? cvt(X, (long long)rr*KIN + k, f) : 0.0f;
  }
  __syncthreads();
  int row = row0 + threadIdx.y;
  if(row >= NN) return;
  float acc = 0.0f;
#pragma unroll
  for(int k = 0; k < KIN; k++) acc += Xl[threadIdx.y][k] * Wl[k*KOUT + threadIdx.x];
  C[(long long)row*KOUT + threadIdx.x] = acc;
}

template<int KIN, int KOUT>
__global__ void k_gemm_f(const float* __restrict__ X, const float* __restrict__ W,
                         float* __restrict__ C){
  constexpr int R = 256 / KOUT;
  __shared__ float Wl[KIN * KOUT];
  __shared__ float Xl[R][KIN];
  int tid = threadIdx.y * KOUT + threadIdx.x;
  for(int i = tid; i < KIN*KOUT; i += 256) Wl[i] = W[i];
  int row0 = blockIdx.x * R;
  for(int i = tid; i < R*KIN; i += 256){
    int r = i / KIN, k = i - r*KIN;
    int rr = row0 + r;
    Xl[r][k] = (rr < NN) ? X[(long long)rr*KIN + k] : 0.0f;
  }
  __syncthreads();
  int row = row0 + threadIdx.y;
  if(row >= NN) return;
  float acc = 0.0f;
#pragma unroll
  for(int k = 0; k < KIN; k++) acc += Xl[threadIdx.y][k] * Wl[k*KOUT + threadIdx.x];
  C[(long long)row*KOUT + threadIdx.x] = acc;
}

// per (node, head) attention scores s = <h, a_src>, d = <h, a_dst>
template<int C>
__global__ void k_gat_scores(const float* __restrict__ Hg, const float* __restrict__ asrc,
                             const float* __restrict__ adst, float* __restrict__ sS, float* __restrict__ sD){
  int i = blockIdx.x*256 + threadIdx.x;
  if(i >= NN*2) return;
  int node = i >> 1, h = i & 1;
  const float* hp = Hg + (long long)node*(2*C) + h*C;
  float s = 0.0f, d = 0.0f;
#pragma unroll
  for(int c = 0; c < C; c++){
    float v = hp[c];
    s += v * asrc[h*C + c];
    d += v * adst[h*C + c];
  }
  sS[i] = s; sD[i] = d;
}

// ---------------- gather aggregations (one wave per dst node) ----------------
// GCN: B[n][l] = relu( dinv[n] * sum_src A[src][l]*dinv[src] + bias[l] )
__global__ void k_gcn_gather(const int* __restrict__ rowptr, const int* __restrict__ rowend,
                             const int* __restrict__ srcidx, const float* __restrict__ dinv,
                             const float* __restrict__ A, const float* __restrict__ bias,
                             float* __restrict__ B){
  int wid = threadIdx.x >> 6, lane = threadIdx.x & 63;
  int n = blockIdx.x*4 + wid;
  if(n >= NN) return;
  int s0 = rowptr[n], s1 = rowend[n];
  float acc = 0.0f;
  for(int i = s0; i < s1; i++){
    int src = srcidx[i];
    acc += A[(long long)src*64 + lane] * dinv[src];
  }
  float v = acc*dinv[n] + bias[lane];
  B[(long long)n*64 + lane] = fmaxf(v, 0.0f);
}

// GAT1 (heads=2, C=64, concat): full segment-softmax + aggregate + bias + relu
__global__ void k_gat1_gather(const int* __restrict__ rowptr, const int* __restrict__ rowend,
                              const int* __restrict__ srcidx, const float* __restrict__ sS,
                              const float* __restrict__ sD, const float* __restrict__ Hg,
                              const float* __restrict__ bias, float* __restrict__ B){
  int wid = threadIdx.x >> 6, lane = threadIdx.x & 63;
  int n = blockIdx.x*4 + wid;
  if(n >= NN) return;
  int s0 = rowptr[n], s1 = rowend[n];
  float d0 = sD[n*2], d1 = sD[n*2+1];
  // phase A: per-lane online (m,z) per head over strided edges
  float m0 = -1e30f, z0 = 0.0f, m1 = -1e30f, z1 = 0.0f;
  for(int i = s0 + lane; i < s1; i += 64){
    int src = srcidx[i];
    float e0 = sS[src*2]   + d0; e0 = e0 > 0.0f ? e0 : 0.2f*e0;
    float e1 = sS[src*2+1] + d1; e1 = e1 > 0.0f ? e1 : 0.2f*e1;
    if(e0 > m0){ z0 *= __expf(m0 - e0); m0 = e0; }
    z0 += __expf(e0 - m0);
    if(e1 > m1){ z1 *= __expf(m1 - e1); m1 = e1; }
    z1 += __expf(e1 - m1);
  }
  for(int off = 32; off; off >>= 1){
    float mo = __shfl_xor(m0, off), zo = __shfl_xor(z0, off);
    float mn = fmaxf(m0, mo);
    z0 = z0*__expf(m0 - mn) + zo*__expf(mo - mn); m0 = mn;
    mo = __shfl_xor(m1, off); zo = __shfl_xor(z1, off);
    mn = fmaxf(m1, mo);
    z1 = z1*__expf(m1 - mn) + zo*__expf(mo - mn); m1 = mn;
  }
  // phase B: weighted accumulate; lane owns channels lane (h0) and 64+lane (h1)
  float acc0 = 0.0f, acc1 = 0.0f;
  for(int i = s0; i < s1; i++){
    int src = srcidx[i];
    float e0 = sS[src*2]   + d0; e0 = e0 > 0.0f ? e0 : 0.2f*e0;
    float e1 = sS[src*2+1] + d1; e1 = e1 > 0.0f ? e1 : 0.2f*e1;
    float w0 = __expf(e0 - m0), w1 = __expf(e1 - m1);
    acc0 += Hg[(long long)src*128 + lane]      * w0;
    acc1 += Hg[(long long)src*128 + 64 + lane] * w1;
  }
  float o0 = acc0/(z0 + 1e-16f) + bias[lane];
  float o1 = acc1/(z1 + 1e-16f) + bias[64 + lane];
  B[(long long)n*128 + lane]      = fmaxf(o0, 0.0f);
  B[(long long)n*128 + 64 + lane] = fmaxf(o1, 0.0f);
}

// GAT2 (heads=2, C=32, mean) + bias + log_softmax + dtype-flagged output
__global__ void k_gat2_final(const int* __restrict__ rowptr, const int* __restrict__ rowend,
                             const int* __restrict__ srcidx, const float* __restrict__ sS,
                             const float* __restrict__ sD, const float* __restrict__ Hg,
                             const float* __restrict__ bias, void* __restrict__ out,
                             const int* __restrict__ flag){
  int wid = threadIdx.x >> 6, lane = threadIdx.x & 63;
  int n = blockIdx.x*4 + wid;
  if(n >= NN) return;
  int s0 = rowptr[n], s1 = rowend[n];
  float d0 = sD[n*2], d1 = sD[n*2+1];
  float m0 = -1e30f, z0 = 0.0f, m1 = -1e30f, z1 = 0.0f;
  for(int i = s0 + lane; i < s1; i += 64){
    int src = srcidx[i];
    float e0 = sS[src*2]   + d0; e0 = e0 > 0.0f ? e0 : 0.2f*e0;
    float e1 = sS[src*2+1] + d1; e1 = e1 > 0.0f ? e1 : 0.2f*e1;
    if(e0 > m0){ z0 *= __expf(m0 - e0); m0 = e0; }
    z0 += __expf(e0 - m0);
    if(e1 > m1){ z1 *= __expf(m1 - e1); m1 = e1; }
    z1 += __expf(e1 - m1);
  }
  for(int off = 32; off; off >>= 1){
    float mo = __shfl_xor(m0, off), zo = __shfl_xor(z0, off);
    float mn = fmaxf(m0, mo);
    z0 = z0*__expf(m0 - mn) + zo*__expf(mo - mn); m0 = mn;
    mo = __shfl_xor(m1, off); zo = __shfl_xor(z1, off);
    mn = fmaxf(m1, mo);
    z1 = z1*__expf(m1 - mn) + zo*__expf(mo - mn); m1 = mn;
  }
  int h = lane >> 5;                          // my channel's head (j=lane, C=32)
  float mh = h ? m1 : m0, zh = h ? z1 : z0, dh = h ? d1 : d0;
  float acc = 0.0f;
  for(int i = s0; i < s1; i++){
    int src = srcidx[i];
    float eh = sS[src*2 + h] + dh; eh = eh > 0.0f ? eh : 0.2f*eh;
    acc += Hg[(long long)src*64 + lane] * __expf(eh - mh);
  }
  float o = acc/(zh + 1e-16f);
  float o2 = __shfl_down(o, 32);              // lane<32 gets head-1 partner
  o = 0.5f*(o + o2) + ((lane < 32) ? bias[lane] : 0.0f);
  // log_softmax over 32 classes held one-per-lane in lanes 0..31
  float mx = o;
  for(int off = 16; off; off >>= 1) mx = fmaxf(mx, __shfl_xor(mx, off, 32));
  float s = __expf(o - mx);
  for(int off = 16; off; off >>= 1) s += __shfl_xor(s, off, 32);
  float r = o - (mx + __logf(s));
  if(lane < 32){
    if(*flag) ((float*)out)[(long long)n*32 + lane] = r;
    else      ((bf16*)out)[(long long)n*32 + lane] = __float2bfloat16(r);
  }
}

extern "C" void kernel_launch(void* const* d_in, const int* in_sizes, int n_in,
                              void* d_out, int out_size, void* d_ws, size_t ws_size,
                              hipStream_t stream) {
  const void* x   = d_in[0];
  const int*  ei  = (const int*)d_in[1];

  // workspace layout:
  // A[NN*128] f32 | B[NN*128] f32 | dinv[NN] | sS[2NN] | sD[2NN] |
  // rowptr[NN] i32 | cursor[NN] i32 | counts[NN] i32 | srcidx[NT] i32 | Wc[29344] | flag
  float* A    = (float*)d_ws;
  float* B    = A + (size_t)NN*128;
  float* dinv = B + (size_t)NN*128;
  float* sS   = dinv + NN;
  float* sD   = sS + 2*NN;
  int* rowptr = (int*)(sD + 2*NN);
  int* cursor = rowptr + NN;
  int* counts = cursor + NN;
  int* srcidx = counts + NN;
  float* Wc   = (float*)(srcidx + NT);
  int*  flag  = (int*)(Wc + 29344);

  const float* W1c  = Wc;
  const float* b1c  = Wc + 8192;
  const float* W2c  = Wc + 8256;
  const float* b2c  = Wc + 12352;
  const float* Wg1c = Wc + 12416;
  const float* as1c = Wc + 20608;
  const float* ad1c = Wc + 20736;
  const float* bg1c = Wc + 20864;
  const float* Wg2c = Wc + 20992;
  const float* as2c = Wc + 29184;
  const float* ad2c = Wc + 29248;
  const float* bg2c = Wc + 29312;

  auto nb = [](long long t){ return dim3((unsigned)((t + 255)/256)); };
  dim3 gnodes((NN + 3)/4);   // 4 waves/block, 1 wave per node

  // dtype detect + weight conversion
  k_detect<<<1, 256, 0, stream>>>(d_in[2], 8192, flag);
  SrcPtrs sp;
  for(int i = 0; i < 12; i++) sp.p[i] = d_in[2 + i];
  k_cvtall<<<12, 256, 0, stream>>>(sp, Wc, flag);

  // CSR build (shared by all 4 aggregations)
  k_init_counts<<<nb(NN), 256, 0, stream>>>(counts);
  k_count_edges<<<nb(NE), 256, 0, stream>>>(ei, counts);
  k_scan<<<1, 1024, 0, stream>>>(counts, rowptr, cursor, dinv);
  k_fill<<<nb(NT), 256, 0, stream>>>(ei, cursor, srcidx);
  // after k_fill: cursor[n] == row end

  // ---- GCN1 ----
  k_gemm_in<128,64><<<dim3((NN+3)/4), dim3(64,4), 0, stream>>>(x, W1c, A, flag);
  k_gcn_gather<<<gnodes, 256, 0, stream>>>(rowptr, cursor, srcidx, dinv, A, b1c, B);

  // ---- GCN2 ----
  k_gemm_f<64,64><<<dim3((NN+3)/4), dim3(64,4), 0, stream>>>(B, W2c, A);
  k_gcn_gather<<<gnodes, 256, 0, stream>>>(rowptr, cursor, srcidx, dinv, A, b2c, B);

  // ---- GAT1: heads=2, C=64, concat ----
  k_gemm_f<64,128><<<dim3((NN+1)/2), dim3(128,2), 0, stream>>>(B, Wg1c, A);
  k_gat_scores<64><<<nb((long long)NN*2), 256, 0, stream>>>(A, as1c, ad1c, sS, sD);
  k_gat1_gather<<<gnodes, 256, 0, stream>>>(rowptr, cursor, srcidx, sS, sD, A, bg1c, B);

  // ---- GAT2: heads=2, C=32, mean + log_softmax ----
  k_gemm_f<128,64><<<dim3((NN+3)/4), dim3(64,4), 0, stream>>>(B, Wg2c, A);
  k_gat_scores<32><<<nb((long long)NN*2), 256, 0, stream>>>(A, as2c, ad2c, sS, sD);
  k_gat2_final<<<gnodes, 256, 0, stream>>>(rowptr, cursor, srcidx, sS, sD, A, bg2c, d_out, flag);
}

// Round 5
// 759.694 us; speedup vs baseline: 5.4697x; 1.1768x over previous
//
#include <hip/hip_runtime.h>
#include <hip/hip_bf16.h>

typedef __hip_bfloat16 bf16;

constexpr int NN = 50000;           // nodes
constexpr int NE = 800000;          // edges (without self loops)
constexpr int NT = NE + NN;         // edges incl self loops
constexpr int NSCB = (NN + 255)/256; // 196 scan blocks

// flag-selected load: f32 storage vs bf16 storage
__device__ __forceinline__ float cvt(const void* p, long long i, int f32){
  return f32 ? ((const float*)p)[i] : __bfloat162float(((const bf16*)p)[i]);
}

// Storage-dtype detector (see R2 notes): flag=1 => f32 storage, 0 => bf16.
__global__ void k_detect(const void* w, int n, int* flag){
  __shared__ int bad;
  if(threadIdx.x == 0) bad = 0;
  __syncthreads();
  const unsigned short* p = (const unsigned short*)w;
  int local = 0;
  for(int i = threadIdx.x; i < n; i += 256){
    int e = (p[i] >> 7) & 0xFF;
    if(e >= 0xC0) local = 1;
  }
  if(local) atomicOr(&bad, 1);
  __syncthreads();
  if(threadIdx.x == 0) *flag = bad;
}

struct SrcPtrs { const void* p[12]; };
__global__ void k_cvtall(SrcPtrs sp, float* Wc, const int* flag){
  const int sz[12]  = {8192,64,4096,64,8192,128,128,128,8192,64,64,32};
  const int off[12] = {0,8192,8256,12352,12416,20608,20736,20864,20992,29184,29248,29312};
  int b = blockIdx.x;
  int f = *flag;
  const void* src = sp.p[b];
  float* dst = Wc + off[b];
  int n = sz[b];
  for(int i = threadIdx.x; i < n; i += 256) dst[i] = cvt(src, i, f);
}

// ---------------- CSR build (dst-bucketed, self-loops included) ----------------
__global__ void k_init_counts(int* __restrict__ counts){
  int i = blockIdx.x*256 + threadIdx.x;
  if(i < NN) counts[i] = 1;          // self loop
}
__global__ void k_count_edges(const int* __restrict__ ei, int* __restrict__ counts){
  int e = blockIdx.x*256 + threadIdx.x;
  if(e < NE) atomicAdd(&counts[ei[NE + e]], 1);
}
// phase 1: per-block sums
__global__ void k_scan1(const int* __restrict__ counts, int* __restrict__ bsum){
  __shared__ int sh[256];
  int i = blockIdx.x*256 + threadIdx.x;
  sh[threadIdx.x] = (i < NN) ? counts[i] : 0;
  __syncthreads();
  for(int off = 128; off; off >>= 1){
    if(threadIdx.x < off) sh[threadIdx.x] += sh[threadIdx.x + off];
    __syncthreads();
  }
  if(threadIdx.x == 0) bsum[blockIdx.x] = sh[0];
}
// phase 2: exclusive scan of NSCB block sums (single tiny block)
__global__ void k_scan2(int* __restrict__ bsum){
  __shared__ int sh[2][256];
  int t = threadIdx.x;
  sh[0][t] = (t < NSCB) ? bsum[t] : 0;
  __syncthreads();
  int cur = 0;
  for(int off = 1; off < 256; off <<= 1){
    int nxt = cur^1;
    int v = sh[cur][t];
    if(t >= off) v += sh[cur][t-off];
    sh[nxt][t] = v;
    __syncthreads();
    cur = nxt;
  }
  if(t < NSCB) bsum[t] = (t == 0) ? 0 : sh[cur][t-1];
}
// phase 3: local scan + apply; writes rowptr, self-loop entry, cursor, dinv
__global__ void k_scan3(const int* __restrict__ counts, const int* __restrict__ bsum,
                        int* __restrict__ rowptr, int* __restrict__ cursor,
                        float* __restrict__ dinv, int* __restrict__ srcidx){
  __shared__ int sh[2][256];
  int t = threadIdx.x;
  int i = blockIdx.x*256 + t;
  int c = (i < NN) ? counts[i] : 0;
  sh[0][t] = c;
  __syncthreads();
  int cur = 0;
  for(int off = 1; off < 256; off <<= 1){
    int nxt = cur^1;
    int v = sh[cur][t];
    if(t >= off) v += sh[cur][t-off];
    sh[nxt][t] = v;
    __syncthreads();
    cur = nxt;
  }
  if(i < NN){
    int excl = bsum[blockIdx.x] + sh[cur][t] - c;
    rowptr[i] = excl;
    srcidx[excl] = i;        // self-loop at row start, no atomic needed
    cursor[i] = excl + 1;    // edges fill after it
    dinv[i] = rsqrtf((float)c);
  }
}
// fill real edges (order within a bucket irrelevant for sums)
__global__ void k_fill(const int* __restrict__ ei, int* __restrict__ cursor,
                       int* __restrict__ srcidx){
  int e = blockIdx.x*256 + threadIdx.x;
  if(e < NE){
    int dst = ei[NE + e];
    int pos = atomicAdd(&cursor[dst], 1);
    srcidx[pos] = ei[e];
  }
}
// after k_fill, cursor[n] == row end for node n.

// ---------------- dense layers ----------------
template<int KIN, int KOUT>
__global__ void k_gemm_in(const void* __restrict__ X, const float* __restrict__ W,
                          float* __restrict__ C, const int* __restrict__ flag){
  constexpr int R = 256 / KOUT;
  __shared__ float Wl[KIN * KOUT];
  __shared__ float Xl[R][KIN];
  int tid = threadIdx.y * KOUT + threadIdx.x;
  int f = *flag;
  for(int i = tid; i < KIN*KOUT; i += 256) Wl[i] = W[i];
  int row0 = blockIdx.x * R;
  for(int i = tid; i < R*KIN; i += 256){
    int r = i / KIN, k = i - r*KIN;
    int rr = row0 + r;
    Xl[r][k] = (rr < NN) ? cvt(X, (long long)rr*KIN + k, f) : 0.0f;
  }
  __syncthreads();
  int row = row0 + threadIdx.y;
  if(row >= NN) return;
  float acc = 0.0f;
#pragma unroll
  for(int k = 0; k < KIN; k++) acc += Xl[threadIdx.y][k] * Wl[k*KOUT + threadIdx.x];
  C[(long long)row*KOUT + threadIdx.x] = acc;
}

template<int KIN, int KOUT>
__global__ void k_gemm_f(const float* __restrict__ X, const float* __restrict__ W,
                         float* __restrict__ C){
  constexpr int R = 256 / KOUT;
  __shared__ float Wl[KIN * KOUT];
  __shared__ float Xl[R][KIN];
  int tid = threadIdx.y * KOUT + threadIdx.x;
  for(int i = tid; i < KIN*KOUT; i += 256) Wl[i] = W[i];
  int row0 = blockIdx.x * R;
  for(int i = tid; i < R*KIN; i += 256){
    int r = i / KIN, k = i - r*KIN;
    int rr = row0 + r;
    Xl[r][k] = (rr < NN) ? X[(long long)rr*KIN + k] : 0.0f;
  }
  __syncthreads();
  int row = row0 + threadIdx.y;
  if(row >= NN) return;
  float acc = 0.0f;
#pragma unroll
  for(int k = 0; k < KIN; k++) acc += Xl[threadIdx.y][k] * Wl[k*KOUT + threadIdx.x];
  C[(long long)row*KOUT + threadIdx.x] = acc;
}

// per (node, head) attention scores s = <h, a_src>, d = <h, a_dst>
template<int C>
__global__ void k_gat_scores(const float* __restrict__ Hg, const float* __restrict__ asrc,
                             const float* __restrict__ adst, float* __restrict__ sS, float* __restrict__ sD){
  int i = blockIdx.x*256 + threadIdx.x;
  if(i >= NN*2) return;
  int node = i >> 1, h = i & 1;
  const float* hp = Hg + (long long)node*(2*C) + h*C;
  float s = 0.0f, d = 0.0f;
#pragma unroll
  for(int c = 0; c < C; c++){
    float v = hp[c];
    s += v * asrc[h*C + c];
    d += v * adst[h*C + c];
  }
  sS[i] = s; sD[i] = d;
}

// ---------------- gather aggregations (one wave per dst node) ----------------
// GCN: B[n][l] = relu( dinv[n] * sum_src A[src][l]*dinv[src] + bias[l] )
__global__ void k_gcn_gather(const int* __restrict__ rowptr, const int* __restrict__ rowend,
                             const int* __restrict__ srcidx, const float* __restrict__ dinv,
                             const float* __restrict__ A, const float* __restrict__ bias,
                             float* __restrict__ B){
  int wid = threadIdx.x >> 6, lane = threadIdx.x & 63;
  int n = blockIdx.x*4 + wid;
  if(n >= NN) return;
  int s0 = rowptr[n], s1 = rowend[n];
  float acc = 0.0f;
  for(int i = s0; i < s1; i++){
    int src = srcidx[i];
    acc += A[(long long)src*64 + lane] * dinv[src];
  }
  float v = acc*dinv[n] + bias[lane];
  B[(long long)n*64 + lane] = fmaxf(v, 0.0f);
}

// GAT1 (heads=2, C=64, concat): full segment-softmax + aggregate + bias + relu
__global__ void k_gat1_gather(const int* __restrict__ rowptr, const int* __restrict__ rowend,
                              const int* __restrict__ srcidx, const float* __restrict__ sS,
                              const float* __restrict__ sD, const float* __restrict__ Hg,
                              const float* __restrict__ bias, float* __restrict__ B){
  int wid = threadIdx.x >> 6, lane = threadIdx.x & 63;
  int n = blockIdx.x*4 + wid;
  if(n >= NN) return;
  int s0 = rowptr[n], s1 = rowend[n];
  float d0 = sD[n*2], d1 = sD[n*2+1];
  // phase A: per-lane online (m,z) per head over strided edges
  float m0 = -1e30f, z0 = 0.0f, m1 = -1e30f, z1 = 0.0f;
  for(int i = s0 + lane; i < s1; i += 64){
    int src = srcidx[i];
    float e0 = sS[src*2]   + d0; e0 = e0 > 0.0f ? e0 : 0.2f*e0;
    float e1 = sS[src*2+1] + d1; e1 = e1 > 0.0f ? e1 : 0.2f*e1;
    if(e0 > m0){ z0 *= __expf(m0 - e0); m0 = e0; }
    z0 += __expf(e0 - m0);
    if(e1 > m1){ z1 *= __expf(m1 - e1); m1 = e1; }
    z1 += __expf(e1 - m1);
  }
  for(int off = 32; off; off >>= 1){
    float mo = __shfl_xor(m0, off), zo = __shfl_xor(z0, off);
    float mn = fmaxf(m0, mo);
    z0 = z0*__expf(m0 - mn) + zo*__expf(mo - mn); m0 = mn;
    mo = __shfl_xor(m1, off); zo = __shfl_xor(z1, off);
    mn = fmaxf(m1, mo);
    z1 = z1*__expf(m1 - mn) + zo*__expf(mo - mn); m1 = mn;
  }
  // phase B: weighted accumulate; lane owns channels lane (h0) and 64+lane (h1)
  float acc0 = 0.0f, acc1 = 0.0f;
  for(int i = s0; i < s1; i++){
    int src = srcidx[i];
    float e0 = sS[src*2]   + d0; e0 = e0 > 0.0f ? e0 : 0.2f*e0;
    float e1 = sS[src*2+1] + d1; e1 = e1 > 0.0f ? e1 : 0.2f*e1;
    float w0 = __expf(e0 - m0), w1 = __expf(e1 - m1);
    acc0 += Hg[(long long)src*128 + lane]      * w0;
    acc1 += Hg[(long long)src*128 + 64 + lane] * w1;
  }
  float o0 = acc0/(z0 + 1e-16f) + bias[lane];
  float o1 = acc1/(z1 + 1e-16f) + bias[64 + lane];
  B[(long long)n*128 + lane]      = fmaxf(o0, 0.0f);
  B[(long long)n*128 + 64 + lane] = fmaxf(o1, 0.0f);
}

// GAT2 (heads=2, C=32, mean) + bias + log_softmax + dtype-flagged output
__global__ void k_gat2_final(const int* __restrict__ rowptr, const int* __restrict__ rowend,
                             const int* __restrict__ srcidx, const float* __restrict__ sS,
                             const float* __restrict__ sD, const float* __restrict__ Hg,
                             const float* __restrict__ bias, void* __restrict__ out,
                             const int* __restrict__ flag){
  int wid = threadIdx.x >> 6, lane = threadIdx.x & 63;
  int n = blockIdx.x*4 + wid;
  if(n >= NN) return;
  int s0 = rowptr[n], s1 = rowend[n];
  float d0 = sD[n*2], d1 = sD[n*2+1];
  float m0 = -1e30f, z0 = 0.0f, m1 = -1e30f, z1 = 0.0f;
  for(int i = s0 + lane; i < s1; i += 64){
    int src = srcidx[i];
    float e0 = sS[src*2]   + d0; e0 = e0 > 0.0f ? e0 : 0.2f*e0;
    float e1 = sS[src*2+1] + d1; e1 = e1 > 0.0f ? e1 : 0.2f*e1;
    if(e0 > m0){ z0 *= __expf(m0 - e0); m0 = e0; }
    z0 += __expf(e0 - m0);
    if(e1 > m1){ z1 *= __expf(m1 - e1); m1 = e1; }
    z1 += __expf(e1 - m1);
  }
  for(int off = 32; off; off >>= 1){
    float mo = __shfl_xor(m0, off), zo = __shfl_xor(z0, off);
    float mn = fmaxf(m0, mo);
    z0 = z0*__expf(m0 - mn) + zo*__expf(mo - mn); m0 = mn;
    mo = __shfl_xor(m1, off); zo = __shfl_xor(z1, off);
    mn = fmaxf(m1, mo);
    z1 = z1*__expf(m1 - mn) + zo*__expf(mo - mn); m1 = mn;
  }
  int h = lane >> 5;                          // my channel's head (j=lane, C=32)
  float mh = h ? m1 : m0, zh = h ? z1 : z0, dh = h ? d1 : d0;
  float acc = 0.0f;
  for(int i = s0; i < s1; i++){
    int src = srcidx[i];
    float eh = sS[src*2 + h] + dh; eh = eh > 0.0f ? eh : 0.2f*eh;
    acc += Hg[(long long)src*64 + lane] * __expf(eh - mh);
  }
  float o = acc/(zh + 1e-16f);
  float o2 = __shfl_down(o, 32);              // lane<32 gets head-1 partner
  o = 0.5f*(o + o2) + ((lane < 32) ? bias[lane] : 0.0f);
  // log_softmax over 32 classes held one-per-lane in lanes 0..31
  float mx = o;
  for(int off = 16; off; off >>= 1) mx = fmaxf(mx, __shfl_xor(mx, off, 32));
  float s = __expf(o - mx);
  for(int off = 16; off; off >>= 1) s += __shfl_xor(s, off, 32);
  float r = o - (mx + __logf(s));
  if(lane < 32){
    if(*flag) ((float*)out)[(long long)n*32 + lane] = r;
    else      ((bf16*)out)[(long long)n*32 + lane] = __float2bfloat16(r);
  }
}

extern "C" void kernel_launch(void* const* d_in, const int* in_sizes, int n_in,
                              void* d_out, int out_size, void* d_ws, size_t ws_size,
                              hipStream_t stream) {
  const void* x   = d_in[0];
  const int*  ei  = (const int*)d_in[1];

  // workspace layout:
  // A[NN*128] f32 | B[NN*128] f32 | dinv[NN] | sS[2NN] | sD[2NN] |
  // rowptr[NN] | cursor[NN] | counts[NN] | bsum[256] | srcidx[NT] | Wc[29344] | flag
  float* A    = (float*)d_ws;
  float* B    = A + (size_t)NN*128;
  float* dinv = B + (size_t)NN*128;
  float* sS   = dinv + NN;
  float* sD   = sS + 2*NN;
  int* rowptr = (int*)(sD + 2*NN);
  int* cursor = rowptr + NN;
  int* counts = cursor + NN;
  int* bsum   = counts + NN;
  int* srcidx = bsum + 256;
  float* Wc   = (float*)(srcidx + NT);
  int*  flag  = (int*)(Wc + 29344);

  const float* W1c  = Wc;
  const float* b1c  = Wc + 8192;
  const float* W2c  = Wc + 8256;
  const float* b2c  = Wc + 12352;
  const float* Wg1c = Wc + 12416;
  const float* as1c = Wc + 20608;
  const float* ad1c = Wc + 20736;
  const float* bg1c = Wc + 20864;
  const float* Wg2c = Wc + 20992;
  const float* as2c = Wc + 29184;
  const float* ad2c = Wc + 29248;
  const float* bg2c = Wc + 29312;

  auto nb = [](long long t){ return dim3((unsigned)((t + 255)/256)); };
  dim3 gnodes((NN + 3)/4);   // 4 waves/block, 1 wave per node

  // dtype detect + weight conversion
  k_detect<<<1, 256, 0, stream>>>(d_in[2], 8192, flag);
  SrcPtrs sp;
  for(int i = 0; i < 12; i++) sp.p[i] = d_in[2 + i];
  k_cvtall<<<12, 256, 0, stream>>>(sp, Wc, flag);

  // CSR build (shared by all 4 aggregations) — 3-phase parallel scan
  k_init_counts<<<nb(NN), 256, 0, stream>>>(counts);
  k_count_edges<<<nb(NE), 256, 0, stream>>>(ei, counts);
  k_scan1<<<NSCB, 256, 0, stream>>>(counts, bsum);
  k_scan2<<<1, 256, 0, stream>>>(bsum);
  k_scan3<<<NSCB, 256, 0, stream>>>(counts, bsum, rowptr, cursor, dinv, srcidx);
  k_fill<<<nb(NE), 256, 0, stream>>>(ei, cursor, srcidx);
  // after k_fill: cursor[n] == row end

  // ---- GCN1 ----
  k_gemm_in<128,64><<<dim3((NN+3)/4), dim3(64,4), 0, stream>>>(x, W1c, A, flag);
  k_gcn_gather<<<gnodes, 256, 0, stream>>>(rowptr, cursor, srcidx, dinv, A, b1c, B);

  // ---- GCN2 ----
  k_gemm_f<64,64><<<dim3((NN+3)/4), dim3(64,4), 0, stream>>>(B, W2c, A);
  k_gcn_gather<<<gnodes, 256, 0, stream>>>(rowptr, cursor, srcidx, dinv, A, b2c, B);

  // ---- GAT1: heads=2, C=64, concat ----
  k_gemm_f<64,128><<<dim3((NN+1)/2), dim3(128,2), 0, stream>>>(B, Wg1c, A);
  k_gat_scores<64><<<nb((long long)NN*2), 256, 0, stream>>>(A, as1c, ad1c, sS, sD);
  k_gat1_gather<<<gnodes, 256, 0, stream>>>(rowptr, cursor, srcidx, sS, sD, A, bg1c, B);

  // ---- GAT2: heads=2, C=32, mean + log_softmax ----
  k_gemm_f<128,64><<<dim3((NN+3)/4), dim3(64,4), 0, stream>>>(B, Wg2c, A);
  k_gat_scores<32><<<nb((long long)NN*2), 256, 0, stream>>>(A, as2c, ad2c, sS, sD);
  k_gat2_final<<<gnodes, 256, 0, stream>>>(rowptr, cursor, srcidx, sS, sD, A, bg2c, d_out, flag);
}